// Round 26
// baseline (97.748 us; speedup 1.0000x reference)
//
#include <hip/hip_runtime.h>
#include <math.h>

#define BB 32
#define SS 2048
#define EE 6144
#define KS2 12   // K-split gemm2 (K=6144, 512 k per block)
#define NCH 4    // Chebyshev nodes for attention softmax interpolation

typedef __bf16 bf16x8 __attribute__((ext_vector_type(8)));
typedef float f32x16 __attribute__((ext_vector_type(16)));
typedef float f32x4 __attribute__((ext_vector_type(4)));

// ---------------- fused [MLP-tail +] LN + attention + residual + gx-pack ----------------
// grid (SS/256, BB); block 512 = 8 waves.
// Chebyshev-interpolated softmax (NCH nodes) as in round 25.
// Epilogue: writes xout, pstat partial {sum,sumsq}, and ubf = bf16(gml*xout)
// in B-fragment layout (this block owns exactly its 256 k's of row b).
__global__ __launch_bounds__(512) void k_attn(const float* __restrict__ xin,
                                              float* __restrict__ xout,
                                              const float* __restrict__ g,
                                              const float* __restrict__ be,
                                              const float* __restrict__ ipw,
                                              const float* __restrict__ ipb,
                                              const float* __restrict__ owp,
                                              const float* __restrict__ obp,
                                              float* __restrict__ stats,
                                              const float* __restrict__ mlpPart,
                                              const float* __restrict__ b2,
                                              float* __restrict__ pstat,
                                              const float* __restrict__ gml,
                                              __bf16* __restrict__ ubf) {
  int b = blockIdx.y;
  const float* xrow = xin + b * SS;
  __shared__ float rowbuf[SS];        // 8 KB
  __shared__ float2 uv[SS];           // 16 KB
  __shared__ float red[16], red2[16], redP[8];
  __shared__ float gxs[256];
  __shared__ float smu, srs, sqc, sqw, skm;
  __shared__ float ldsS[8][NCH], ldsT[8][NCH];
  __shared__ float bcS[NCH], bcT[NCH];
  int tid = threadIdx.x;
  int lane = tid & 63, wid = tid >> 6;

  const float CN[NCH] = { 0.92387953f,  0.38268343f, -0.38268343f, -0.92387953f};
  const float WN[NCH] = { 0.38268343f, -0.92387953f,  0.92387953f, -0.38268343f};

  // phase 0: build input row + LN stats inline
  float s, s2;
  {
    float4* rb4 = reinterpret_cast<float4*>(rowbuf);
    const float4* xr4 = reinterpret_cast<const float4*>(xrow);
    float4 o;
    if (mlpPart) {
      const float4* b24 = reinterpret_cast<const float4*>(b2);
      float4 xv = xr4[tid];
      float4 bv = b24[tid];
      float4 pv[KS2];
#pragma unroll
      for (int ks = 0; ks < KS2; ks++)
        pv[ks] = reinterpret_cast<const float4*>(mlpPart + (size_t)ks * (32 * SS) + (size_t)b * SS)[tid];
      o.x = xv.x + bv.x; o.y = xv.y + bv.y; o.z = xv.z + bv.z; o.w = xv.w + bv.w;
#pragma unroll
      for (int ks = 0; ks < KS2; ks++) {
        o.x += pv[ks].x; o.y += pv[ks].y; o.z += pv[ks].z; o.w += pv[ks].w;
      }
      rb4[tid] = o;
    } else {
      o = xr4[tid];
      rb4[tid] = o;
    }
    s = (o.x + o.y) + (o.z + o.w);
    s2 = fmaf(o.x, o.x, fmaf(o.y, o.y, fmaf(o.z, o.z, o.w * o.w)));
  }
  for (int off = 32; off; off >>= 1) { s += __shfl_down(s, off); s2 += __shfl_down(s2, off); }
  if (lane == 0) { red[wid] = s; red[8 + wid] = s2; }
  __syncthreads();
  if (tid == 0) {
    float ts = 0.f, ts2 = 0.f;
#pragma unroll
    for (int w = 0; w < 8; w++) { ts += red[w]; ts2 += red[8 + w]; }
    float mu = ts / SS;
    float var = ts2 / SS - mu * mu;
    smu = mu; srs = rsqrtf(var + 1e-5f);
    if (stats && blockIdx.x == 0) {
      stats[b] = mu;
      stats[BB + b] = (ts2 - SS * mu * mu) / (SS - 1);
    }
  }
  __syncthreads();
  float mu = smu, rs = srs;
  float wq = ipw[0], wk = ipw[1], wv = ipw[2];
  float bq = ipb[0], bk = ipb[1], bv = ipb[2];

  // phase 2: stage (u, v) + u extremes
  float umax = -1e30f, umin = 1e30f;
  for (int j = tid; j < SS; j += 512) {
    float u = (rowbuf[j] - mu) * rs * g[j] + be[j];
    uv[j] = make_float2(u, fmaf(u, wv, bv));
    umax = fmaxf(umax, u);
    umin = fminf(umin, u);
  }
  for (int off = 32; off; off >>= 1) {
    umax = fmaxf(umax, __shfl_down(umax, off));
    umin = fminf(umin, __shfl_down(umin, off));
  }
  if (lane == 0) { red2[wid] = umax; red2[8 + wid] = umin; }
  __syncthreads();
  if (tid == 0) {
    float ux = -1e30f, un = 1e30f;
#pragma unroll
    for (int w = 0; w < 8; w++) { ux = fmaxf(ux, red2[w]); un = fminf(un, red2[8 + w]); }
    float ka = fmaf(ux, wk, bk), kb = fmaf(un, wk, bk);
    skm = 0.5f * (ka + kb);
    float qa = fmaf(ux, wq, bq), qb2 = fmaf(un, wq, bq);
    float qlo = fminf(qa, qb2), qhi = fmaxf(qa, qb2);
    sqc = 0.5f * (qlo + qhi);
    sqw = fmaxf(0.5f * (qhi - qlo), 1e-12f);
  }
  __syncthreads();
  float qc = sqc, qw = sqw, km = skm;

  const float L2E = 1.4426950408889634f;
  float qn[NCH], an[NCH];
#pragma unroll
  for (int n = 0; n < NCH; n++) {
    qn[n] = fmaf(qw, CN[n], qc);
    an[n] = L2E * qn[n];
  }

  // phase 3a: S_n, T_n over all j
  float Sa[NCH], Ta[NCH];
#pragma unroll
  for (int n = 0; n < NCH; n++) { Sa[n] = 0.f; Ta[n] = 0.f; }
  for (int j = tid; j < SS; j += 512) {
    float2 c = uv[j];
    float kd = fmaf(c.x, wk, bk) - km;
#pragma unroll
    for (int n = 0; n < NCH; n++) {
      float e = __builtin_amdgcn_exp2f(an[n] * kd);
      Sa[n] += e;
      Ta[n] = fmaf(e, c.y, Ta[n]);
    }
  }
#pragma unroll
  for (int n = 0; n < NCH; n++) {
    for (int off = 32; off; off >>= 1) {
      Sa[n] += __shfl_down(Sa[n], off);
      Ta[n] += __shfl_down(Ta[n], off);
    }
  }
  if (lane == 0) {
#pragma unroll
    for (int n = 0; n < NCH; n++) { ldsS[wid][n] = Sa[n]; ldsT[wid][n] = Ta[n]; }
  }
  __syncthreads();
  if (tid < NCH) {
    float ss = 0.f, tt = 0.f;
#pragma unroll
    for (int w = 0; w < 8; w++) { ss += ldsS[w][tid]; tt += ldsT[w][tid]; }
    bcS[tid] = ss; bcT[tid] = tt;
  }
  __syncthreads();

  // phase 3b: barycentric output + pstat partials + gx staging
  float po = 0.f, po2 = 0.f;
  if (tid < 256) {
    int i = (blockIdx.x << 8) + tid;
    float u = uv[i].x;
    float q = fmaf(u, wq, bq);
    float tiny = qw * 1e-10f;
    float num = 0.f, den = 0.f;
#pragma unroll
    for (int n = 0; n < NCH; n++) {
      float d = q - qn[n];
      d = copysignf(fmaxf(fabsf(d), tiny), d);
      float cc = WN[n] / d;
      num = fmaf(cc, bcT[n], num);
      den = fmaf(cc, bcS[n], den);
    }
    float ov = fmaf(num / den, owp[0], obp[0]) + rowbuf[i];
    xout[b * SS + i] = ov;
    gxs[tid] = gml[i] * ov;
    po = ov;
    po2 = ov * ov;
  }
  for (int off = 32; off; off >>= 1) {
    po += __shfl_down(po, off);
    po2 += __shfl_down(po2, off);
  }
  if (lane == 0 && wid < 4) { redP[wid] = po; redP[4 + wid] = po2; }
  __syncthreads();
  if (tid == 0) {
    pstat[blockIdx.x * BB + b] = (redP[0] + redP[1]) + (redP[2] + redP[3]);
    pstat[8 * BB + blockIdx.x * BB + b] = (redP[4] + redP[5]) + (redP[6] + redP[7]);
  }
  // pack bf16(g*x) into B-fragment layout: group gi = bx*32+t, elems gxs[t*8..]
  if (tid < 32) {
    bf16x8 o;
#pragma unroll
    for (int j = 0; j < 8; j++) o[j] = (__bf16)gxs[tid * 8 + j];
    *reinterpret_cast<bf16x8*>(ubf + (size_t)((blockIdx.x << 5) + tid) * 256 + b * 8) = o;
  }
}

// ---- shared GEMM chunk body over 128 k (round-18 layout, verified) ----
__device__ __forceinline__ void gemm_chunk(const float* __restrict__ wp,
                                           const __bf16* __restrict__ up,
                                           f32x16& acc) {
  bf16x8 ub[8];
  f32x4 wa[8], wb2[8];
#pragma unroll
  for (int t = 0; t < 8; ++t) ub[t] = *reinterpret_cast<const bf16x8*>(up + (t << 9));
#pragma unroll
  for (int t = 0; t < 4; ++t) {
    wa[2 * t]     = *reinterpret_cast<const f32x4*>(wp + (t << 4));
    wa[2 * t + 1] = *reinterpret_cast<const f32x4*>(wp + (t << 4) + 4);
  }
#pragma unroll
  for (int t = 4; t < 8; ++t) {
    wb2[2 * (t - 4)]     = *reinterpret_cast<const f32x4*>(wp + (t << 4));
    wb2[2 * (t - 4) + 1] = *reinterpret_cast<const f32x4*>(wp + (t << 4) + 4);
  }
#pragma unroll
  for (int t = 0; t < 4; ++t) {
    bf16x8 av;
    av[0] = (__bf16)wa[2 * t][0];     av[1] = (__bf16)wa[2 * t][1];
    av[2] = (__bf16)wa[2 * t][2];     av[3] = (__bf16)wa[2 * t][3];
    av[4] = (__bf16)wa[2 * t + 1][0]; av[5] = (__bf16)wa[2 * t + 1][1];
    av[6] = (__bf16)wa[2 * t + 1][2]; av[7] = (__bf16)wa[2 * t + 1][3];
    acc = __builtin_amdgcn_mfma_f32_32x32x16_bf16(av, ub[t], acc, 0, 0, 0);
  }
#pragma unroll
  for (int t = 0; t < 4; ++t) {
    bf16x8 av;
    av[0] = (__bf16)wb2[2 * t][0];     av[1] = (__bf16)wb2[2 * t][1];
    av[2] = (__bf16)wb2[2 * t][2];     av[3] = (__bf16)wb2[2 * t][3];
    av[4] = (__bf16)wb2[2 * t + 1][0]; av[5] = (__bf16)wb2[2 * t + 1][1];
    av[6] = (__bf16)wb2[2 * t + 1][2]; av[7] = (__bf16)wb2[2 * t + 1][3];
    acc = __builtin_amdgcn_mfma_f32_32x32x16_bf16(av, ub[4 + t], acc, 0, 0, 0);
  }
}

// ---------------- gemm1 full-K over gx = bf16(g*x), LN applied via correction ----------------
// h_pre[e][b] = rs_b*(A1[e][b] - mu_b*G1[e]) + B1[e],  A1 = W1·gx (MFMA),
// G1[e] = sum_k W1[e][k]*g[k], B1[e] = sum_k W1[e][k]*be[k] (inline fp32 dots).
__global__ __launch_bounds__(256, 2) void k_gemm1(const __bf16* __restrict__ Ubf,
                                                  const float* __restrict__ W,
                                                  const float* __restrict__ gml,
                                                  const float* __restrict__ bml,
                                                  const float* __restrict__ pstat,
                                                  const float* __restrict__ bias,
                                                  __bf16* __restrict__ hbf) {
  __shared__ float ls[3][16][64];  // 12 KB cross-wave acc reduce
  __shared__ float st[32][33];     // epilogue staging
  __shared__ float glw[4][32], blw[4][32];
  __shared__ float smub[32], srsb[32];
  int tid = threadIdx.x;
  int w = tid >> 6, lane = tid & 63;
  int l31 = lane & 31, h = lane >> 5;
  int e0 = blockIdx.x << 5;

  f32x16 acc = {0.f, 0.f, 0.f, 0.f, 0.f, 0.f, 0.f, 0.f,
                0.f, 0.f, 0.f, 0.f, 0.f, 0.f, 0.f, 0.f};
  float gl = 0.f, bl = 0.f;
#pragma unroll
  for (int c = 0; c < 4; ++c) {
    int kc = (w << 9) + (c << 7);
    const float* wp = W + (size_t)(e0 + l31) * SS + kc + (h << 3);
    const __bf16* up = Ubf + (size_t)((kc >> 3) + h) * 256 + (l31 << 3);
    const float* gp = gml + kc + (h << 3);
    const float* bp = bml + kc + (h << 3);
    // G1/B1 dot partials (transient g/be regs, uniform per half-wave)
#pragma unroll
    for (int t = 0; t < 8; ++t) {
      f32x4 wv0 = *reinterpret_cast<const f32x4*>(wp + (t << 4));
      f32x4 wv1 = *reinterpret_cast<const f32x4*>(wp + (t << 4) + 4);
      f32x4 g0 = *reinterpret_cast<const f32x4*>(gp + (t << 4));
      f32x4 g1 = *reinterpret_cast<const f32x4*>(gp + (t << 4) + 4);
      f32x4 b0 = *reinterpret_cast<const f32x4*>(bp + (t << 4));
      f32x4 b1 = *reinterpret_cast<const f32x4*>(bp + (t << 4) + 4);
#pragma unroll
      for (int i = 0; i < 4; ++i) {
        gl = fmaf(wv0[i], g0[i], gl); gl = fmaf(wv1[i], g1[i], gl);
        bl = fmaf(wv0[i], b0[i], bl); bl = fmaf(wv1[i], b1[i], bl);
      }
    }
    gemm_chunk(wp, up, acc);
  }
  gl += __shfl_xor(gl, 32);
  bl += __shfl_xor(bl, 32);
  if (h == 0) { glw[w][l31] = gl; blw[w][l31] = bl; }
  if (tid < 32) {
    float sb = 0.f, sb2 = 0.f;
#pragma unroll
    for (int c = 0; c < 8; c++) {
      sb += pstat[c * BB + tid];
      sb2 += pstat[8 * BB + c * BB + tid];
    }
    float m = sb * (1.f / SS);
    smub[tid] = m;
    srsb[tid] = rsqrtf(sb2 * (1.f / SS) - m * m + 1e-5f);
  }

  if (w) {
#pragma unroll
    for (int r = 0; r < 16; ++r) ls[w - 1][r][lane] = acc[r];
  }
  __syncthreads();
  if (w == 0) {
#pragma unroll
    for (int r = 0; r < 16; ++r) {
      float v = acc[r] + ls[0][r][lane] + ls[1][r][lane] + ls[2][r][lane];
      int row = (r & 3) + ((r >> 2) << 3) + (h << 2);
      st[row][l31] = v;
    }
  }
  __syncthreads();
  if (tid < 128) {
    int eg = tid >> 5, b = tid & 31;
    float mub = smub[b], rsb = srsb[b];
    bf16x8 o;
#pragma unroll
    for (int j = 0; j < 8; j++) {
      int el = eg * 8 + j;
      float G1 = (glw[0][el] + glw[1][el]) + (glw[2][el] + glw[3][el]);
      float B1 = (blw[0][el] + blw[1][el]) + (blw[2][el] + blw[3][el]);
      float v = rsb * (st[el][b] - mub * G1) + B1 + bias[e0 + el];
      o[j] = (__bf16)(v >= 0.f ? v : 0.5f * v);
    }
    *reinterpret_cast<bf16x8*>(hbf + (size_t)((e0 >> 3) + eg) * 256 + b * 8) = o;
  }
}

// ---------------- gemm2 split-K, b-major partial store part[ks][b][s] ----------------
__global__ __launch_bounds__(256, 4) void k_gemm2(const __bf16* __restrict__ Ubf,
                                                  const float* __restrict__ W,
                                                  float* __restrict__ part,
                                                  int K) {
  __shared__ float ls[3][16][64];
  __shared__ float st[32][33];
  int tid = threadIdx.x;
  int w = tid >> 6, lane = tid & 63;
  int l31 = lane & 31, h = lane >> 5;
  int s0 = blockIdx.x << 5;
  int kc = (blockIdx.y << 9) + (w << 7);
  const float* wp = W + (size_t)(s0 + l31) * K + kc + (h << 3);
  const __bf16* up = Ubf + (size_t)((kc >> 3) + h) * 256 + (l31 << 3);

  f32x16 acc = {0.f, 0.f, 0.f, 0.f, 0.f, 0.f, 0.f, 0.f,
                0.f, 0.f, 0.f, 0.f, 0.f, 0.f, 0.f, 0.f};
  gemm_chunk(wp, up, acc);

  if (w) {
#pragma unroll
    for (int r = 0; r < 16; ++r) ls[w - 1][r][lane] = acc[r];
  }
  __syncthreads();
  if (w == 0) {
#pragma unroll
    for (int r = 0; r < 16; ++r) {
      float v = acc[r] + ls[0][r][lane] + ls[1][r][lane] + ls[2][r][lane];
      int row = (r & 3) + ((r >> 2) << 3) + (h << 2);
      st[row][l31] = v;
    }
  }
  __syncthreads();
  {
    float* out = part + (size_t)blockIdx.y * (32 * SS);
    int bb = tid >> 3, i0 = (tid & 7) << 2;
    float4 o4;
    o4.x = st[i0 + 0][bb];
    o4.y = st[i0 + 1][bb];
    o4.z = st[i0 + 2][bb];
    o4.w = st[i0 + 3][bb];
    *reinterpret_cast<float4*>(out + (size_t)bb * SS + s0 + i0) = o4;
  }
}

// ---------------- final: row = xA + b2 + sum part; renorm to original stats ----------------
__global__ __launch_bounds__(256) void k_final(const float* __restrict__ xbuf,
                                               const float* __restrict__ part,
                                               const float* __restrict__ b2,
                                               const float* __restrict__ stats,
                                               float* __restrict__ out) {
  int b = blockIdx.x;
  __shared__ float rowbuf[SS];
  __shared__ float sm[8];
  __shared__ float smu, srs;
  int tid = threadIdx.x;
  float4* rb4 = reinterpret_cast<float4*>(rowbuf);
  const float4* xr4 = reinterpret_cast<const float4*>(xbuf + (size_t)b * SS);
  const float4* b24 = reinterpret_cast<const float4*>(b2);
#pragma unroll
  for (int it = 0; it < 2; ++it) {
    int jj = tid + (it << 8);
    float4 xv = xr4[jj];
    float4 bv = b24[jj];
    float4 pv[KS2];
#pragma unroll
    for (int ks = 0; ks < KS2; ks++)
      pv[ks] = reinterpret_cast<const float4*>(part + (size_t)ks * (32 * SS) + (size_t)b * SS)[jj];
    float4 o;
    o.x = xv.x + bv.x; o.y = xv.y + bv.y; o.z = xv.z + bv.z; o.w = xv.w + bv.w;
#pragma unroll
    for (int ks = 0; ks < KS2; ks++) {
      o.x += pv[ks].x; o.y += pv[ks].y; o.z += pv[ks].z; o.w += pv[ks].w;
    }
    rb4[jj] = o;
  }
  __syncthreads();

  float s = 0.f, s2 = 0.f;
  for (int j = tid; j < SS; j += 256) { float v = rowbuf[j]; s += v; s2 += v * v; }
  for (int off = 32; off; off >>= 1) { s += __shfl_down(s, off); s2 += __shfl_down(s2, off); }
  int lane = tid & 63, wid = tid >> 6;
  if (lane == 0) { sm[wid] = s; sm[4 + wid] = s2; }
  __syncthreads();
  if (tid == 0) {
    float ts = sm[0] + sm[1] + sm[2] + sm[3];
    float ts2 = sm[4] + sm[5] + sm[6] + sm[7];
    float mu = ts / SS;
    float var = (ts2 - SS * mu * mu) / (SS - 1);
    smu = mu;
    srs = rsqrtf(var + 2.220446049250313e-16f);
  }
  __syncthreads();
  float mu = smu, rs = srs;
  float scale = sqrtf(stats[BB + b] + 2.220446049250313e-16f);
  float mean0 = stats[b];
  for (int j = tid; j < SS; j += 256) {
    out[(size_t)b * SS + j] = (rowbuf[j] - mu) * rs * scale + mean0;
  }
}

extern "C" void kernel_launch(void* const* d_in, const int* in_sizes, int n_in,
                              void* d_out, int out_size, void* d_ws, size_t ws_size,
                              hipStream_t stream) {
  const float* x         = (const float*)d_in[0];
  const float* attn_ln_g = (const float*)d_in[1];
  const float* attn_ln_b = (const float*)d_in[2];
  const float* ipw       = (const float*)d_in[3];
  const float* ipb       = (const float*)d_in[4];
  const float* out_w     = (const float*)d_in[5];
  const float* out_b     = (const float*)d_in[6];
  const float* mlp_ln_g  = (const float*)d_in[7];
  const float* mlp_ln_b  = (const float*)d_in[8];
  const float* W1        = (const float*)d_in[9];
  const float* b1        = (const float*)d_in[10];
  const float* W2        = (const float*)d_in[11];
  const float* b2        = (const float*)d_in[12];

  float* ws    = (float*)d_ws;
  float* xA    = ws;                              // 65536 f (attn-0 output)
  float* xB    = xA + BB * SS;                    // 65536 f (attn-1 output)
  __bf16* ubf  = (__bf16*)(xB + BB * SS);         // 65536 bf16 (g*x, B-frag layout)
  __bf16* hbf  = (__bf16*)(xB + BB * SS + 32768); // 196608 bf16 (98304 f)
  float* part  = xB + BB * SS + 32768 + 98304;    // 786432 f (3.1 MB), [ks][b][s]
  float* stats = part + (size_t)KS2 * 32 * SS;    // 64 f
  float* pstat = stats + 64;                      // 512 f

  // ---- layer 0 ----
  k_attn<<<dim3(SS / 256, BB), 512, 0, stream>>>(x, xA,
                                                 attn_ln_g, attn_ln_b,
                                                 ipw, ipb, out_w, out_b,
                                                 stats, nullptr, nullptr, pstat,
                                                 mlp_ln_g, ubf);
  k_gemm1<<<EE / 32, 256, 0, stream>>>(ubf, W1, mlp_ln_g, mlp_ln_b, pstat, b1, hbf);
  k_gemm2<<<dim3(SS / 32, KS2), 256, 0, stream>>>(hbf, W2, part, EE);

  // ---- layer 1 (attn fuses layer-0 MLP tail) ----
  k_attn<<<dim3(SS / 256, BB), 512, 0, stream>>>(xA, xB,
                                                 attn_ln_g + SS, attn_ln_b + SS,
                                                 ipw + 3, ipb + 3, out_w + 1, out_b + 1,
                                                 nullptr, part, b2, pstat,
                                                 mlp_ln_g + SS, ubf);
  k_gemm1<<<EE / 32, 256, 0, stream>>>(ubf, W1 + (size_t)EE * SS,
                                       mlp_ln_g + SS, mlp_ln_b + SS, pstat, b1 + EE, hbf);
  k_gemm2<<<dim3(SS / 32, KS2), 256, 0, stream>>>(hbf, W2 + (size_t)SS * EE, part, EE);

  // ---- final (fuses layer-1 MLP tail) ----
  k_final<<<BB, 256, 0, stream>>>(xB, part, b2 + SS, stats, (float*)d_out);
}

// Round 27
// 85.516 us; speedup vs baseline: 1.1430x; 1.1430x over previous
//
#include <hip/hip_runtime.h>
#include <math.h>

#define BB 32
#define SS 2048
#define EE 6144
#define KS2 12   // K-split gemm2 (K=6144, 512 k per block)
#define NCH 4    // Chebyshev nodes for attention softmax interpolation

typedef __bf16 bf16x8 __attribute__((ext_vector_type(8)));
typedef float f32x16 __attribute__((ext_vector_type(16)));
typedef float f32x4 __attribute__((ext_vector_type(4)));

// ---------------- fused [MLP-tail +] LN + attention + residual + gx-pack ----------------
// grid (SS/256, BB); block 512 = 8 waves.  Chebyshev softmax (NCH nodes).
// Epilogue: xout, pstat partial {sum,sumsq}, ubf = bf16(gml*xout) (B-frag layout).
__global__ __launch_bounds__(512) void k_attn(const float* __restrict__ xin,
                                              float* __restrict__ xout,
                                              const float* __restrict__ g,
                                              const float* __restrict__ be,
                                              const float* __restrict__ ipw,
                                              const float* __restrict__ ipb,
                                              const float* __restrict__ owp,
                                              const float* __restrict__ obp,
                                              float* __restrict__ stats,
                                              const float* __restrict__ mlpPart,
                                              const float* __restrict__ b2,
                                              float* __restrict__ pstat,
                                              const float* __restrict__ gml,
                                              __bf16* __restrict__ ubf) {
  int b = blockIdx.y;
  const float* xrow = xin + b * SS;
  __shared__ float rowbuf[SS];        // 8 KB
  __shared__ float2 uv[SS];           // 16 KB
  __shared__ float red[16], red2[16], redP[8];
  __shared__ float gxs[256];
  __shared__ float smu, srs, sqc, sqw, skm;
  __shared__ float ldsS[8][NCH], ldsT[8][NCH];
  __shared__ float bcS[NCH], bcT[NCH];
  int tid = threadIdx.x;
  int lane = tid & 63, wid = tid >> 6;

  const float CN[NCH] = { 0.92387953f,  0.38268343f, -0.38268343f, -0.92387953f};
  const float WN[NCH] = { 0.38268343f, -0.92387953f,  0.92387953f, -0.38268343f};

  // phase 0: build input row + LN stats inline
  float s, s2;
  {
    float4* rb4 = reinterpret_cast<float4*>(rowbuf);
    const float4* xr4 = reinterpret_cast<const float4*>(xrow);
    float4 o;
    if (mlpPart) {
      const float4* b24 = reinterpret_cast<const float4*>(b2);
      float4 xv = xr4[tid];
      float4 bv = b24[tid];
      float4 pv[KS2];
#pragma unroll
      for (int ks = 0; ks < KS2; ks++)
        pv[ks] = reinterpret_cast<const float4*>(mlpPart + (size_t)ks * (32 * SS) + (size_t)b * SS)[tid];
      o.x = xv.x + bv.x; o.y = xv.y + bv.y; o.z = xv.z + bv.z; o.w = xv.w + bv.w;
#pragma unroll
      for (int ks = 0; ks < KS2; ks++) {
        o.x += pv[ks].x; o.y += pv[ks].y; o.z += pv[ks].z; o.w += pv[ks].w;
      }
      rb4[tid] = o;
    } else {
      o = xr4[tid];
      rb4[tid] = o;
    }
    s = (o.x + o.y) + (o.z + o.w);
    s2 = fmaf(o.x, o.x, fmaf(o.y, o.y, fmaf(o.z, o.z, o.w * o.w)));
  }
  for (int off = 32; off; off >>= 1) { s += __shfl_down(s, off); s2 += __shfl_down(s2, off); }
  if (lane == 0) { red[wid] = s; red[8 + wid] = s2; }
  __syncthreads();
  if (tid == 0) {
    float ts = 0.f, ts2 = 0.f;
#pragma unroll
    for (int w = 0; w < 8; w++) { ts += red[w]; ts2 += red[8 + w]; }
    float mu = ts / SS;
    float var = ts2 / SS - mu * mu;
    smu = mu; srs = rsqrtf(var + 1e-5f);
    if (stats && blockIdx.x == 0) {
      stats[b] = mu;
      stats[BB + b] = (ts2 - SS * mu * mu) / (SS - 1);
    }
  }
  __syncthreads();
  float mu = smu, rs = srs;
  float wq = ipw[0], wk = ipw[1], wv = ipw[2];
  float bq = ipb[0], bk = ipb[1], bv = ipb[2];

  // phase 2: stage (u, v) + u extremes
  float umax = -1e30f, umin = 1e30f;
  for (int j = tid; j < SS; j += 512) {
    float u = (rowbuf[j] - mu) * rs * g[j] + be[j];
    uv[j] = make_float2(u, fmaf(u, wv, bv));
    umax = fmaxf(umax, u);
    umin = fminf(umin, u);
  }
  for (int off = 32; off; off >>= 1) {
    umax = fmaxf(umax, __shfl_down(umax, off));
    umin = fminf(umin, __shfl_down(umin, off));
  }
  if (lane == 0) { red2[wid] = umax; red2[8 + wid] = umin; }
  __syncthreads();
  if (tid == 0) {
    float ux = -1e30f, un = 1e30f;
#pragma unroll
    for (int w = 0; w < 8; w++) { ux = fmaxf(ux, red2[w]); un = fminf(un, red2[8 + w]); }
    float ka = fmaf(ux, wk, bk), kb = fmaf(un, wk, bk);
    skm = 0.5f * (ka + kb);
    float qa = fmaf(ux, wq, bq), qb2 = fmaf(un, wq, bq);
    float qlo = fminf(qa, qb2), qhi = fmaxf(qa, qb2);
    sqc = 0.5f * (qlo + qhi);
    sqw = fmaxf(0.5f * (qhi - qlo), 1e-12f);
  }
  __syncthreads();
  float qc = sqc, qw = sqw, km = skm;

  const float L2E = 1.4426950408889634f;
  float qn[NCH], an[NCH];
#pragma unroll
  for (int n = 0; n < NCH; n++) {
    qn[n] = fmaf(qw, CN[n], qc);
    an[n] = L2E * qn[n];
  }

  // phase 3a: S_n, T_n over all j
  float Sa[NCH], Ta[NCH];
#pragma unroll
  for (int n = 0; n < NCH; n++) { Sa[n] = 0.f; Ta[n] = 0.f; }
  for (int j = tid; j < SS; j += 512) {
    float2 c = uv[j];
    float kd = fmaf(c.x, wk, bk) - km;
#pragma unroll
    for (int n = 0; n < NCH; n++) {
      float e = __builtin_amdgcn_exp2f(an[n] * kd);
      Sa[n] += e;
      Ta[n] = fmaf(e, c.y, Ta[n]);
    }
  }
#pragma unroll
  for (int n = 0; n < NCH; n++) {
    for (int off = 32; off; off >>= 1) {
      Sa[n] += __shfl_down(Sa[n], off);
      Ta[n] += __shfl_down(Ta[n], off);
    }
  }
  if (lane == 0) {
#pragma unroll
    for (int n = 0; n < NCH; n++) { ldsS[wid][n] = Sa[n]; ldsT[wid][n] = Ta[n]; }
  }
  __syncthreads();
  if (tid < NCH) {
    float ss = 0.f, tt = 0.f;
#pragma unroll
    for (int w = 0; w < 8; w++) { ss += ldsS[w][tid]; tt += ldsT[w][tid]; }
    bcS[tid] = ss; bcT[tid] = tt;
  }
  __syncthreads();

  // phase 3b: barycentric output + pstat partials + gx staging
  float po = 0.f, po2 = 0.f;
  if (tid < 256) {
    int i = (blockIdx.x << 8) + tid;
    float u = uv[i].x;
    float q = fmaf(u, wq, bq);
    float tiny = qw * 1e-10f;
    float num = 0.f, den = 0.f;
#pragma unroll
    for (int n = 0; n < NCH; n++) {
      float d = q - qn[n];
      d = copysignf(fmaxf(fabsf(d), tiny), d);
      float cc = WN[n] / d;
      num = fmaf(cc, bcT[n], num);
      den = fmaf(cc, bcS[n], den);
    }
    float ov = fmaf(num / den, owp[0], obp[0]) + rowbuf[i];
    xout[b * SS + i] = ov;
    gxs[tid] = gml[i] * ov;
    po = ov;
    po2 = ov * ov;
  }
  for (int off = 32; off; off >>= 1) {
    po += __shfl_down(po, off);
    po2 += __shfl_down(po2, off);
  }
  if (lane == 0 && wid < 4) { redP[wid] = po; redP[4 + wid] = po2; }
  __syncthreads();
  if (tid == 0) {
    pstat[blockIdx.x * BB + b] = (redP[0] + redP[1]) + (redP[2] + redP[3]);
    pstat[8 * BB + blockIdx.x * BB + b] = (redP[4] + redP[5]) + (redP[6] + redP[7]);
  }
  if (tid < 32) {
    bf16x8 o;
#pragma unroll
    for (int j = 0; j < 8; j++) o[j] = (__bf16)gxs[tid * 8 + j];
    *reinterpret_cast<bf16x8*>(ubf + (size_t)((blockIdx.x << 5) + tid) * 256 + b * 8) = o;
  }
}

// ---- shared GEMM chunk body over 128 k (round-18 layout, verified) ----
__device__ __forceinline__ void gemm_chunk(const float* __restrict__ wp,
                                           const __bf16* __restrict__ up,
                                           f32x16& acc) {
  bf16x8 ub[8];
  f32x4 wa[8], wb2[8];
#pragma unroll
  for (int t = 0; t < 8; ++t) ub[t] = *reinterpret_cast<const bf16x8*>(up + (t << 9));
#pragma unroll
  for (int t = 0; t < 4; ++t) {
    wa[2 * t]     = *reinterpret_cast<const f32x4*>(wp + (t << 4));
    wa[2 * t + 1] = *reinterpret_cast<const f32x4*>(wp + (t << 4) + 4);
  }
#pragma unroll
  for (int t = 4; t < 8; ++t) {
    wb2[2 * (t - 4)]     = *reinterpret_cast<const f32x4*>(wp + (t << 4));
    wb2[2 * (t - 4) + 1] = *reinterpret_cast<const f32x4*>(wp + (t << 4) + 4);
  }
#pragma unroll
  for (int t = 0; t < 4; ++t) {
    bf16x8 av;
    av[0] = (__bf16)wa[2 * t][0];     av[1] = (__bf16)wa[2 * t][1];
    av[2] = (__bf16)wa[2 * t][2];     av[3] = (__bf16)wa[2 * t][3];
    av[4] = (__bf16)wa[2 * t + 1][0]; av[5] = (__bf16)wa[2 * t + 1][1];
    av[6] = (__bf16)wa[2 * t + 1][2]; av[7] = (__bf16)wa[2 * t + 1][3];
    acc = __builtin_amdgcn_mfma_f32_32x32x16_bf16(av, ub[t], acc, 0, 0, 0);
  }
#pragma unroll
  for (int t = 0; t < 4; ++t) {
    bf16x8 av;
    av[0] = (__bf16)wb2[2 * t][0];     av[1] = (__bf16)wb2[2 * t][1];
    av[2] = (__bf16)wb2[2 * t][2];     av[3] = (__bf16)wb2[2 * t][3];
    av[4] = (__bf16)wb2[2 * t + 1][0]; av[5] = (__bf16)wb2[2 * t + 1][1];
    av[6] = (__bf16)wb2[2 * t + 1][2]; av[7] = (__bf16)wb2[2 * t + 1][3];
    acc = __builtin_amdgcn_mfma_f32_32x32x16_bf16(av, ub[4 + t], acc, 0, 0, 0);
  }
}

// ---------------- gemm1 full-K over gx, LN via correction; W loaded ONCE ----------------
// h_pre[e][b] = rs_b*(A1[e][b] - mu_b*G1[e]) + B1[e]; A1 = W1·gx (MFMA);
// G1/B1 dots reuse the same W registers as the MFMA A-fragments.
__global__ __launch_bounds__(256, 2) void k_gemm1(const __bf16* __restrict__ Ubf,
                                                  const float* __restrict__ W,
                                                  const float* __restrict__ gml,
                                                  const float* __restrict__ bml,
                                                  const float* __restrict__ pstat,
                                                  const float* __restrict__ bias,
                                                  __bf16* __restrict__ hbf) {
  __shared__ float ls[3][16][64];
  __shared__ float st[32][33];
  __shared__ float glw[4][32], blw[4][32];
  __shared__ float smub[32], srsb[32];
  int tid = threadIdx.x;
  int w = tid >> 6, lane = tid & 63;
  int l31 = lane & 31, h = lane >> 5;
  int e0 = blockIdx.x << 5;

  f32x16 acc = {0.f, 0.f, 0.f, 0.f, 0.f, 0.f, 0.f, 0.f,
                0.f, 0.f, 0.f, 0.f, 0.f, 0.f, 0.f, 0.f};
  float gl = 0.f, bl = 0.f;
#pragma unroll
  for (int c = 0; c < 4; ++c) {
    int kc = (w << 9) + (c << 7);
    const float* wp = W + (size_t)(e0 + l31) * SS + kc + (h << 3);
    const __bf16* up = Ubf + (size_t)((kc >> 3) + h) * 256 + (l31 << 3);
    const float* gp = gml + kc + (h << 3);
    const float* bp = bml + kc + (h << 3);
    bf16x8 ub[8];
#pragma unroll
    for (int t = 0; t < 8; ++t) ub[t] = *reinterpret_cast<const bf16x8*>(up + (t << 9));
#pragma unroll
    for (int t = 0; t < 8; ++t) {
      f32x4 wv0 = *reinterpret_cast<const f32x4*>(wp + (t << 4));
      f32x4 wv1 = *reinterpret_cast<const f32x4*>(wp + (t << 4) + 4);
      f32x4 g0 = *reinterpret_cast<const f32x4*>(gp + (t << 4));
      f32x4 g1 = *reinterpret_cast<const f32x4*>(gp + (t << 4) + 4);
      f32x4 b0 = *reinterpret_cast<const f32x4*>(bp + (t << 4));
      f32x4 b1 = *reinterpret_cast<const f32x4*>(bp + (t << 4) + 4);
#pragma unroll
      for (int i = 0; i < 4; ++i) {
        gl = fmaf(wv0[i], g0[i], gl); gl = fmaf(wv1[i], g1[i], gl);
        bl = fmaf(wv0[i], b0[i], bl); bl = fmaf(wv1[i], b1[i], bl);
      }
      bf16x8 av;
      av[0] = (__bf16)wv0[0]; av[1] = (__bf16)wv0[1];
      av[2] = (__bf16)wv0[2]; av[3] = (__bf16)wv0[3];
      av[4] = (__bf16)wv1[0]; av[5] = (__bf16)wv1[1];
      av[6] = (__bf16)wv1[2]; av[7] = (__bf16)wv1[3];
      acc = __builtin_amdgcn_mfma_f32_32x32x16_bf16(av, ub[t], acc, 0, 0, 0);
    }
  }
  gl += __shfl_xor(gl, 32);
  bl += __shfl_xor(bl, 32);
  if (h == 0) { glw[w][l31] = gl; blw[w][l31] = bl; }
  if (tid < 32) {
    float sb = 0.f, sb2 = 0.f;
#pragma unroll
    for (int c = 0; c < 8; c++) {
      sb += pstat[c * BB + tid];
      sb2 += pstat[8 * BB + c * BB + tid];
    }
    float m = sb * (1.f / SS);
    smub[tid] = m;
    srsb[tid] = rsqrtf(sb2 * (1.f / SS) - m * m + 1e-5f);
  }

  if (w) {
#pragma unroll
    for (int r = 0; r < 16; ++r) ls[w - 1][r][lane] = acc[r];
  }
  __syncthreads();
  if (w == 0) {
#pragma unroll
    for (int r = 0; r < 16; ++r) {
      float v = acc[r] + ls[0][r][lane] + ls[1][r][lane] + ls[2][r][lane];
      int row = (r & 3) + ((r >> 2) << 3) + (h << 2);
      st[row][l31] = v;
    }
  }
  __syncthreads();
  if (tid < 128) {
    int eg = tid >> 5, b = tid & 31;
    float mub = smub[b], rsb = srsb[b];
    bf16x8 o;
#pragma unroll
    for (int j = 0; j < 8; j++) {
      int el = eg * 8 + j;
      float G1 = (glw[0][el] + glw[1][el]) + (glw[2][el] + glw[3][el]);
      float B1 = (blw[0][el] + blw[1][el]) + (blw[2][el] + blw[3][el]);
      float v = rsb * (st[el][b] - mub * G1) + B1 + bias[e0 + el];
      o[j] = (__bf16)(v >= 0.f ? v : 0.5f * v);
    }
    *reinterpret_cast<bf16x8*>(hbf + (size_t)((e0 >> 3) + eg) * 256 + b * 8) = o;
  }
}

// ---------------- gemm2 split-K, b-major partial store part[ks][b][s] ----------------
__global__ __launch_bounds__(256, 4) void k_gemm2(const __bf16* __restrict__ Ubf,
                                                  const float* __restrict__ W,
                                                  float* __restrict__ part,
                                                  int K) {
  __shared__ float ls[3][16][64];
  __shared__ float st[32][33];
  int tid = threadIdx.x;
  int w = tid >> 6, lane = tid & 63;
  int l31 = lane & 31, h = lane >> 5;
  int s0 = blockIdx.x << 5;
  int kc = (blockIdx.y << 9) + (w << 7);
  const float* wp = W + (size_t)(s0 + l31) * K + kc + (h << 3);
  const __bf16* up = Ubf + (size_t)((kc >> 3) + h) * 256 + (l31 << 3);

  f32x16 acc = {0.f, 0.f, 0.f, 0.f, 0.f, 0.f, 0.f, 0.f,
                0.f, 0.f, 0.f, 0.f, 0.f, 0.f, 0.f, 0.f};
  gemm_chunk(wp, up, acc);

  if (w) {
#pragma unroll
    for (int r = 0; r < 16; ++r) ls[w - 1][r][lane] = acc[r];
  }
  __syncthreads();
  if (w == 0) {
#pragma unroll
    for (int r = 0; r < 16; ++r) {
      float v = acc[r] + ls[0][r][lane] + ls[1][r][lane] + ls[2][r][lane];
      int row = (r & 3) + ((r >> 2) << 3) + (h << 2);
      st[row][l31] = v;
    }
  }
  __syncthreads();
  {
    float* out = part + (size_t)blockIdx.y * (32 * SS);
    int bb = tid >> 3, i0 = (tid & 7) << 2;
    float4 o4;
    o4.x = st[i0 + 0][bb];
    o4.y = st[i0 + 1][bb];
    o4.z = st[i0 + 2][bb];
    o4.w = st[i0 + 3][bb];
    *reinterpret_cast<float4*>(out + (size_t)bb * SS + s0 + i0) = o4;
  }
}

// ---------------- final: row = xA + b2 + sum part; renorm to original stats ----------------
__global__ __launch_bounds__(256) void k_final(const float* __restrict__ xbuf,
                                               const float* __restrict__ part,
                                               const float* __restrict__ b2,
                                               const float* __restrict__ stats,
                                               float* __restrict__ out) {
  int b = blockIdx.x;
  __shared__ float rowbuf[SS];
  __shared__ float sm[8];
  __shared__ float smu, srs;
  int tid = threadIdx.x;
  float4* rb4 = reinterpret_cast<float4*>(rowbuf);
  const float4* xr4 = reinterpret_cast<const float4*>(xbuf + (size_t)b * SS);
  const float4* b24 = reinterpret_cast<const float4*>(b2);
#pragma unroll
  for (int it = 0; it < 2; ++it) {
    int jj = tid + (it << 8);
    float4 xv = xr4[jj];
    float4 bv = b24[jj];
    float4 pv[KS2];
#pragma unroll
    for (int ks = 0; ks < KS2; ks++)
      pv[ks] = reinterpret_cast<const float4*>(part + (size_t)ks * (32 * SS) + (size_t)b * SS)[jj];
    float4 o;
    o.x = xv.x + bv.x; o.y = xv.y + bv.y; o.z = xv.z + bv.z; o.w = xv.w + bv.w;
#pragma unroll
    for (int ks = 0; ks < KS2; ks++) {
      o.x += pv[ks].x; o.y += pv[ks].y; o.z += pv[ks].z; o.w += pv[ks].w;
    }
    rb4[jj] = o;
  }
  __syncthreads();

  float s = 0.f, s2 = 0.f;
  for (int j = tid; j < SS; j += 256) { float v = rowbuf[j]; s += v; s2 += v * v; }
  for (int off = 32; off; off >>= 1) { s += __shfl_down(s, off); s2 += __shfl_down(s2, off); }
  int lane = tid & 63, wid = tid >> 6;
  if (lane == 0) { sm[wid] = s; sm[4 + wid] = s2; }
  __syncthreads();
  if (tid == 0) {
    float ts = sm[0] + sm[1] + sm[2] + sm[3];
    float ts2 = sm[4] + sm[5] + sm[6] + sm[7];
    float mu = ts / SS;
    float var = (ts2 - SS * mu * mu) / (SS - 1);
    smu = mu;
    srs = rsqrtf(var + 2.220446049250313e-16f);
  }
  __syncthreads();
  float mu = smu, rs = srs;
  float scale = sqrtf(stats[BB + b] + 2.220446049250313e-16f);
  float mean0 = stats[b];
  for (int j = tid; j < SS; j += 256) {
    out[(size_t)b * SS + j] = (rowbuf[j] - mu) * rs * scale + mean0;
  }
}

extern "C" void kernel_launch(void* const* d_in, const int* in_sizes, int n_in,
                              void* d_out, int out_size, void* d_ws, size_t ws_size,
                              hipStream_t stream) {
  const float* x         = (const float*)d_in[0];
  const float* attn_ln_g = (const float*)d_in[1];
  const float* attn_ln_b = (const float*)d_in[2];
  const float* ipw       = (const float*)d_in[3];
  const float* ipb       = (const float*)d_in[4];
  const float* out_w     = (const float*)d_in[5];
  const float* out_b     = (const float*)d_in[6];
  const float* mlp_ln_g  = (const float*)d_in[7];
  const float* mlp_ln_b  = (const float*)d_in[8];
  const float* W1        = (const float*)d_in[9];
  const float* b1        = (const float*)d_in[10];
  const float* W2        = (const float*)d_in[11];
  const float* b2        = (const float*)d_in[12];

  float* ws    = (float*)d_ws;
  float* xA    = ws;                              // 65536 f (attn-0 output)
  float* xB    = xA + BB * SS;                    // 65536 f (attn-1 output)
  __bf16* ubf  = (__bf16*)(xB + BB * SS);         // 65536 bf16 (g*x, B-frag layout)
  __bf16* hbf  = (__bf16*)(xB + BB * SS + 32768); // 196608 bf16 (98304 f)
  float* part  = xB + BB * SS + 32768 + 98304;    // 786432 f (3.1 MB), [ks][b][s]
  float* stats = part + (size_t)KS2 * 32 * SS;    // 64 f
  float* pstat = stats + 64;                      // 512 f

  // ---- layer 0 ----
  k_attn<<<dim3(SS / 256, BB), 512, 0, stream>>>(x, xA,
                                                 attn_ln_g, attn_ln_b,
                                                 ipw, ipb, out_w, out_b,
                                                 stats, nullptr, nullptr, pstat,
                                                 mlp_ln_g, ubf);
  k_gemm1<<<EE / 32, 256, 0, stream>>>(ubf, W1, mlp_ln_g, mlp_ln_b, pstat, b1, hbf);
  k_gemm2<<<dim3(SS / 32, KS2), 256, 0, stream>>>(hbf, W2, part, EE);

  // ---- layer 1 (attn fuses layer-0 MLP tail) ----
  k_attn<<<dim3(SS / 256, BB), 512, 0, stream>>>(xA, xB,
                                                 attn_ln_g + SS, attn_ln_b + SS,
                                                 ipw + 3, ipb + 3, out_w + 1, out_b + 1,
                                                 nullptr, part, b2, pstat,
                                                 mlp_ln_g + SS, ubf);
  k_gemm1<<<EE / 32, 256, 0, stream>>>(ubf, W1 + (size_t)EE * SS,
                                       mlp_ln_g + SS, mlp_ln_b + SS, pstat, b1 + EE, hbf);
  k_gemm2<<<dim3(SS / 32, KS2), 256, 0, stream>>>(hbf, W2 + (size_t)SS * EE, part, EE);

  // ---- final (fuses layer-1 MLP tail) ----
  k_final<<<BB, 256, 0, stream>>>(xB, part, b2 + SS, stats, (float*)d_out);
}

// Round 28
// 73.627 us; speedup vs baseline: 1.3276x; 1.1615x over previous
//
#include <hip/hip_runtime.h>
#include <math.h>

#define BB 32
#define SS 2048
#define EE 6144
#define KS2 12   // K-split gemm2 (K=6144, 512 k per block)
#define NCH 4    // Chebyshev nodes for attention softmax interpolation

typedef __bf16 bf16x8 __attribute__((ext_vector_type(8)));
typedef float f32x16 __attribute__((ext_vector_type(16)));
typedef float f32x4 __attribute__((ext_vector_type(4)));

// ---------------- fused [MLP-tail +] LN + attention + residual ----------------
// grid (SS/256, BB); block 512 = 8 waves.
// head_dim=1: o_i = T(q_i)/S(q_i), S(q)=sum_j exp(q*(k_j-km)),
// T(q)=sum_j exp(q*(k_j-km))*v_j — analytic in q; evaluate at 4 Chebyshev
// nodes over the row's q-range, barycentric-interpolate per i.
// Error (c*qw/2)^4/4! <= ~1e-4 at this problem's scales (<< bf16 GEMM noise).
// Epilogue emits pstat partial {sum,sumsq} of this block's 256 outputs.
__global__ __launch_bounds__(512) void k_attn(const float* __restrict__ xin,
                                              float* __restrict__ xout,
                                              const float* __restrict__ g,
                                              const float* __restrict__ be,
                                              const float* __restrict__ ipw,
                                              const float* __restrict__ ipb,
                                              const float* __restrict__ owp,
                                              const float* __restrict__ obp,
                                              float* __restrict__ stats,
                                              const float* __restrict__ mlpPart,
                                              const float* __restrict__ b2,
                                              float* __restrict__ pstat) {
  int b = blockIdx.y;
  const float* xrow = xin + b * SS;
  __shared__ float rowbuf[SS];        // 8 KB reconstructed input row
  __shared__ float2 uv[SS];           // (u_j, v_j)  16 KB
  __shared__ float red[16], red2[16], redP[8];
  __shared__ float smu, srs, sqc, sqw, skm;
  __shared__ float ldsS[8][NCH], ldsT[8][NCH];
  __shared__ float bcS[NCH], bcT[NCH];
  int tid = threadIdx.x;
  int lane = tid & 63, wid = tid >> 6;

  // Chebyshev (1st kind, N=4) nodes cos((2i+1)pi/8), weights (-1)^i sin((2i+1)pi/8)
  const float CN[NCH] = { 0.92387953f,  0.38268343f, -0.38268343f, -0.92387953f};
  const float WN[NCH] = { 0.38268343f, -0.92387953f,  0.92387953f, -0.38268343f};

  // phase 0: build input row (one float4/thread) + accumulate LN stats inline
  float s, s2;
  {
    float4* rb4 = reinterpret_cast<float4*>(rowbuf);
    const float4* xr4 = reinterpret_cast<const float4*>(xrow);
    float4 o;
    if (mlpPart) {
      const float4* b24 = reinterpret_cast<const float4*>(b2);
      float4 xv = xr4[tid];
      float4 bv = b24[tid];
      float4 pv[KS2];
#pragma unroll
      for (int ks = 0; ks < KS2; ks++)
        pv[ks] = reinterpret_cast<const float4*>(mlpPart + (size_t)ks * (32 * SS) + (size_t)b * SS)[tid];
      o.x = xv.x + bv.x; o.y = xv.y + bv.y; o.z = xv.z + bv.z; o.w = xv.w + bv.w;
#pragma unroll
      for (int ks = 0; ks < KS2; ks++) {
        o.x += pv[ks].x; o.y += pv[ks].y; o.z += pv[ks].z; o.w += pv[ks].w;
      }
      rb4[tid] = o;
    } else {
      o = xr4[tid];
      rb4[tid] = o;
    }
    s = (o.x + o.y) + (o.z + o.w);
    s2 = fmaf(o.x, o.x, fmaf(o.y, o.y, fmaf(o.z, o.z, o.w * o.w)));
  }
  for (int off = 32; off; off >>= 1) { s += __shfl_down(s, off); s2 += __shfl_down(s2, off); }
  if (lane == 0) { red[wid] = s; red[8 + wid] = s2; }
  __syncthreads();
  if (tid == 0) {
    float ts = 0.f, ts2 = 0.f;
#pragma unroll
    for (int w = 0; w < 8; w++) { ts += red[w]; ts2 += red[8 + w]; }
    float mu = ts / SS;
    float var = ts2 / SS - mu * mu;
    smu = mu; srs = rsqrtf(var + 1e-5f);
    if (stats && blockIdx.x == 0) {
      stats[b] = mu;
      stats[BB + b] = (ts2 - SS * mu * mu) / (SS - 1);
    }
  }
  __syncthreads();
  float mu = smu, rs = srs;
  float wq = ipw[0], wk = ipw[1], wv = ipw[2];
  float bq = ipb[0], bk = ipb[1], bv = ipb[2];

  // phase 2: stage (u, v) into LDS + track u extremes
  float umax = -1e30f, umin = 1e30f;
  for (int j = tid; j < SS; j += 512) {
    float u = (rowbuf[j] - mu) * rs * g[j] + be[j];
    uv[j] = make_float2(u, fmaf(u, wv, bv));
    umax = fmaxf(umax, u);
    umin = fminf(umin, u);
  }
  for (int off = 32; off; off >>= 1) {
    umax = fmaxf(umax, __shfl_down(umax, off));
    umin = fminf(umin, __shfl_down(umin, off));
  }
  if (lane == 0) { red2[wid] = umax; red2[8 + wid] = umin; }
  __syncthreads();
  if (tid == 0) {
    float ux = -1e30f, un = 1e30f;
#pragma unroll
    for (int w = 0; w < 8; w++) { ux = fmaxf(ux, red2[w]); un = fminf(un, red2[8 + w]); }
    float ka = fmaf(ux, wk, bk), kb = fmaf(un, wk, bk);
    skm = 0.5f * (ka + kb);
    float qa = fmaf(ux, wq, bq), qb2 = fmaf(un, wq, bq);
    float qlo = fminf(qa, qb2), qhi = fmaxf(qa, qb2);
    sqc = 0.5f * (qlo + qhi);
    sqw = fmaxf(0.5f * (qhi - qlo), 1e-12f);
  }
  __syncthreads();
  float qc = sqc, qw = sqw, km = skm;

  // node q-values and exp2 coefficients
  const float L2E = 1.4426950408889634f;
  float qn[NCH], an[NCH];
#pragma unroll
  for (int n = 0; n < NCH; n++) {
    qn[n] = fmaf(qw, CN[n], qc);
    an[n] = L2E * qn[n];
  }

  // phase 3a: S_n, T_n over all j (4 j per thread, 4 nodes each)
  float Sa[NCH], Ta[NCH];
#pragma unroll
  for (int n = 0; n < NCH; n++) { Sa[n] = 0.f; Ta[n] = 0.f; }
  for (int j = tid; j < SS; j += 512) {
    float2 c = uv[j];
    float kd = fmaf(c.x, wk, bk) - km;
#pragma unroll
    for (int n = 0; n < NCH; n++) {
      float e = __builtin_amdgcn_exp2f(an[n] * kd);
      Sa[n] += e;
      Ta[n] = fmaf(e, c.y, Ta[n]);
    }
  }
#pragma unroll
  for (int n = 0; n < NCH; n++) {
    for (int off = 32; off; off >>= 1) {
      Sa[n] += __shfl_down(Sa[n], off);
      Ta[n] += __shfl_down(Ta[n], off);
    }
  }
  if (lane == 0) {
#pragma unroll
    for (int n = 0; n < NCH; n++) { ldsS[wid][n] = Sa[n]; ldsT[wid][n] = Ta[n]; }
  }
  __syncthreads();
  if (tid < NCH) {
    float ss = 0.f, tt = 0.f;
#pragma unroll
    for (int w = 0; w < 8; w++) { ss += ldsS[w][tid]; tt += ldsT[w][tid]; }
    bcS[tid] = ss; bcT[tid] = tt;
  }
  __syncthreads();

  // phase 3b: barycentric evaluation, one i per thread (tid < 256),
  // plus partial output-stats for the downstream fused LayerNorm.
  float po = 0.f, po2 = 0.f;
  if (tid < 256) {
    int i = (blockIdx.x << 8) + tid;
    float u = uv[i].x;
    float q = fmaf(u, wq, bq);
    float tiny = qw * 1e-10f;
    float num = 0.f, den = 0.f;
#pragma unroll
    for (int n = 0; n < NCH; n++) {
      float d = q - qn[n];
      d = copysignf(fmaxf(fabsf(d), tiny), d);
      float cc = WN[n] / d;
      num = fmaf(cc, bcT[n], num);
      den = fmaf(cc, bcS[n], den);
    }
    float ov = fmaf(num / den, owp[0], obp[0]) + rowbuf[i];
    xout[b * SS + i] = ov;
    po = ov;
    po2 = ov * ov;
  }
  for (int off = 32; off; off >>= 1) {
    po += __shfl_down(po, off);
    po2 += __shfl_down(po2, off);
  }
  if (lane == 0 && wid < 4) { redP[wid] = po; redP[4 + wid] = po2; }
  __syncthreads();
  if (tid == 0) {
    pstat[blockIdx.x * BB + b] = (redP[0] + redP[1]) + (redP[2] + redP[3]);
    pstat[8 * BB + blockIdx.x * BB + b] = (redP[4] + redP[5]) + (redP[6] + redP[7]);
  }
}

// ---------------- LayerNorm -> bf16 B-fragment layout Ubf[k/8][32][8] ----------------
// Row stats come precomputed from attn's pstat partials (8 per row).
__global__ __launch_bounds__(256) void k_ln_bf(const float* __restrict__ x,
                                               const float* __restrict__ pstat,
                                               const float* __restrict__ g,
                                               const float* __restrict__ be,
                                               __bf16* __restrict__ ubf) {
  int b = blockIdx.x;
  const float* row = x + b * SS;
  float s = 0.f, s2 = 0.f;
#pragma unroll
  for (int c = 0; c < 8; c++) {
    s += pstat[c * BB + b];
    s2 += pstat[8 * BB + c * BB + b];
  }
  float mu = s * (1.f / SS);
  float var = s2 * (1.f / SS) - mu * mu;
  float rs = rsqrtf(var + 1e-5f);
  int t = threadIdx.x;
  float4 v0 = *reinterpret_cast<const float4*>(row + t * 8);
  float4 v1 = *reinterpret_cast<const float4*>(row + t * 8 + 4);
  float4 g0 = *reinterpret_cast<const float4*>(g + t * 8);
  float4 g1 = *reinterpret_cast<const float4*>(g + t * 8 + 4);
  float4 b0 = *reinterpret_cast<const float4*>(be + t * 8);
  float4 b1 = *reinterpret_cast<const float4*>(be + t * 8 + 4);
  bf16x8 o;
  o[0] = (__bf16)((v0.x - mu) * rs * g0.x + b0.x);
  o[1] = (__bf16)((v0.y - mu) * rs * g0.y + b0.y);
  o[2] = (__bf16)((v0.z - mu) * rs * g0.z + b0.z);
  o[3] = (__bf16)((v0.w - mu) * rs * g0.w + b0.w);
  o[4] = (__bf16)((v1.x - mu) * rs * g1.x + b1.x);
  o[5] = (__bf16)((v1.y - mu) * rs * g1.y + b1.y);
  o[6] = (__bf16)((v1.z - mu) * rs * g1.z + b1.z);
  o[7] = (__bf16)((v1.w - mu) * rs * g1.w + b1.w);
  *reinterpret_cast<bf16x8*>(ubf + t * 256 + b * 8) = o;
}

// ---- shared GEMM chunk body over 128 k (round-18 layout, verified) ----
__device__ __forceinline__ void gemm_chunk(const float* __restrict__ wp,
                                           const __bf16* __restrict__ up,
                                           f32x16& acc) {
  bf16x8 ub[8];
  f32x4 wa[8], wb2[8];
#pragma unroll
  for (int t = 0; t < 8; ++t) ub[t] = *reinterpret_cast<const bf16x8*>(up + (t << 9));
#pragma unroll
  for (int t = 0; t < 4; ++t) {
    wa[2 * t]     = *reinterpret_cast<const f32x4*>(wp + (t << 4));
    wa[2 * t + 1] = *reinterpret_cast<const f32x4*>(wp + (t << 4) + 4);
  }
#pragma unroll
  for (int t = 4; t < 8; ++t) {
    wb2[2 * (t - 4)]     = *reinterpret_cast<const f32x4*>(wp + (t << 4));
    wb2[2 * (t - 4) + 1] = *reinterpret_cast<const f32x4*>(wp + (t << 4) + 4);
  }
#pragma unroll
  for (int t = 0; t < 4; ++t) {
    bf16x8 av;
    av[0] = (__bf16)wa[2 * t][0];     av[1] = (__bf16)wa[2 * t][1];
    av[2] = (__bf16)wa[2 * t][2];     av[3] = (__bf16)wa[2 * t][3];
    av[4] = (__bf16)wa[2 * t + 1][0]; av[5] = (__bf16)wa[2 * t + 1][1];
    av[6] = (__bf16)wa[2 * t + 1][2]; av[7] = (__bf16)wa[2 * t + 1][3];
    acc = __builtin_amdgcn_mfma_f32_32x32x16_bf16(av, ub[t], acc, 0, 0, 0);
  }
#pragma unroll
  for (int t = 0; t < 4; ++t) {
    bf16x8 av;
    av[0] = (__bf16)wb2[2 * t][0];     av[1] = (__bf16)wb2[2 * t][1];
    av[2] = (__bf16)wb2[2 * t][2];     av[3] = (__bf16)wb2[2 * t][3];
    av[4] = (__bf16)wb2[2 * t + 1][0]; av[5] = (__bf16)wb2[2 * t + 1][1];
    av[6] = (__bf16)wb2[2 * t + 1][2]; av[7] = (__bf16)wb2[2 * t + 1][3];
    acc = __builtin_amdgcn_mfma_f32_32x32x16_bf16(av, ub[4 + t], acc, 0, 0, 0);
  }
}

// ---------------- gemm1 full-K: h = LeakyReLU(W1 u + b1) -> hbf directly ----------------
__global__ __launch_bounds__(256, 4) void k_gemm1(const __bf16* __restrict__ Ubf,
                                                  const float* __restrict__ W,
                                                  const float* __restrict__ bias,
                                                  __bf16* __restrict__ hbf) {
  __shared__ float ls[3][16][64];  // 12 KB cross-wave reduce
  __shared__ float st[32][33];     // 4.2 KB epilogue staging
  int tid = threadIdx.x;
  int w = tid >> 6, lane = tid & 63;
  int l31 = lane & 31, h = lane >> 5;
  int e0 = blockIdx.x << 5;

  f32x16 acc = {0.f, 0.f, 0.f, 0.f, 0.f, 0.f, 0.f, 0.f,
                0.f, 0.f, 0.f, 0.f, 0.f, 0.f, 0.f, 0.f};
#pragma unroll
  for (int c = 0; c < 4; ++c) {
    int kc = (w << 9) + (c << 7);
    const float* wp = W + (size_t)(e0 + l31) * SS + kc + (h << 3);
    const __bf16* up = Ubf + (size_t)((kc >> 3) + h) * 256 + (l31 << 3);
    gemm_chunk(wp, up, acc);
  }

  if (w) {
#pragma unroll
    for (int r = 0; r < 16; ++r) ls[w - 1][r][lane] = acc[r];
  }
  __syncthreads();
  if (w == 0) {
#pragma unroll
    for (int r = 0; r < 16; ++r) {
      float v = acc[r] + ls[0][r][lane] + ls[1][r][lane] + ls[2][r][lane];
      int row = (r & 3) + ((r >> 2) << 3) + (h << 2);
      st[row][l31] = v;
    }
  }
  __syncthreads();
  if (tid < 128) {
    int eg = tid >> 5, b = tid & 31;
    bf16x8 o;
#pragma unroll
    for (int j = 0; j < 8; j++) {
      float v = st[eg * 8 + j][b] + bias[e0 + eg * 8 + j];
      o[j] = (__bf16)(v >= 0.f ? v : 0.5f * v);
    }
    *reinterpret_cast<bf16x8*>(hbf + (size_t)((e0 >> 3) + eg) * 256 + b * 8) = o;
  }
}

// ---------------- gemm2 split-K, b-major partial store part[ks][b][s] ----------------
__global__ __launch_bounds__(256, 4) void k_gemm2(const __bf16* __restrict__ Ubf,
                                                  const float* __restrict__ W,
                                                  float* __restrict__ part,
                                                  int K) {
  __shared__ float ls[3][16][64];  // 12 KB
  __shared__ float st[32][33];     // 4.2 KB transpose staging
  int tid = threadIdx.x;
  int w = tid >> 6, lane = tid & 63;
  int l31 = lane & 31, h = lane >> 5;
  int s0 = blockIdx.x << 5;
  int kc = (blockIdx.y << 9) + (w << 7);
  const float* wp = W + (size_t)(s0 + l31) * K + kc + (h << 3);
  const __bf16* up = Ubf + (size_t)((kc >> 3) + h) * 256 + (l31 << 3);

  f32x16 acc = {0.f, 0.f, 0.f, 0.f, 0.f, 0.f, 0.f, 0.f,
                0.f, 0.f, 0.f, 0.f, 0.f, 0.f, 0.f, 0.f};
  gemm_chunk(wp, up, acc);

  if (w) {
#pragma unroll
    for (int r = 0; r < 16; ++r) ls[w - 1][r][lane] = acc[r];
  }
  __syncthreads();
  if (w == 0) {
#pragma unroll
    for (int r = 0; r < 16; ++r) {
      float v = acc[r] + ls[0][r][lane] + ls[1][r][lane] + ls[2][r][lane];
      int row = (r & 3) + ((r >> 2) << 3) + (h << 2);   // s_local
      st[row][l31] = v;                                  // [s_local][b]
    }
  }
  __syncthreads();
  // b-major store: thread t -> b = t>>3, s-quad i0 = (t&7)*4
  {
    float* out = part + (size_t)blockIdx.y * (32 * SS);
    int bb = tid >> 3, i0 = (tid & 7) << 2;
    float4 o4;
    o4.x = st[i0 + 0][bb];
    o4.y = st[i0 + 1][bb];
    o4.z = st[i0 + 2][bb];
    o4.w = st[i0 + 3][bb];
    *reinterpret_cast<float4*>(out + (size_t)bb * SS + s0 + i0) = o4;
  }
}

// ---------------- final: row = xA + b2 + sum part; renorm to original stats ----------------
__global__ __launch_bounds__(256) void k_final(const float* __restrict__ xbuf,
                                               const float* __restrict__ part,
                                               const float* __restrict__ b2,
                                               const float* __restrict__ stats,
                                               float* __restrict__ out) {
  int b = blockIdx.x;
  __shared__ float rowbuf[SS];
  __shared__ float sm[8];
  __shared__ float smu, srs;
  int tid = threadIdx.x;
  float4* rb4 = reinterpret_cast<float4*>(rowbuf);
  const float4* xr4 = reinterpret_cast<const float4*>(xbuf + (size_t)b * SS);
  const float4* b24 = reinterpret_cast<const float4*>(b2);
#pragma unroll
  for (int it = 0; it < 2; ++it) {
    int jj = tid + (it << 8);
    float4 xv = xr4[jj];
    float4 bv = b24[jj];
    float4 pv[KS2];
#pragma unroll
    for (int ks = 0; ks < KS2; ks++)
      pv[ks] = reinterpret_cast<const float4*>(part + (size_t)ks * (32 * SS) + (size_t)b * SS)[jj];
    float4 o;
    o.x = xv.x + bv.x; o.y = xv.y + bv.y; o.z = xv.z + bv.z; o.w = xv.w + bv.w;
#pragma unroll
    for (int ks = 0; ks < KS2; ks++) {
      o.x += pv[ks].x; o.y += pv[ks].y; o.z += pv[ks].z; o.w += pv[ks].w;
    }
    rb4[jj] = o;
  }
  __syncthreads();

  float s = 0.f, s2 = 0.f;
  for (int j = tid; j < SS; j += 256) { float v = rowbuf[j]; s += v; s2 += v * v; }
  for (int off = 32; off; off >>= 1) { s += __shfl_down(s, off); s2 += __shfl_down(s2, off); }
  int lane = tid & 63, wid = tid >> 6;
  if (lane == 0) { sm[wid] = s; sm[4 + wid] = s2; }
  __syncthreads();
  if (tid == 0) {
    float ts = sm[0] + sm[1] + sm[2] + sm[3];
    float ts2 = sm[4] + sm[5] + sm[6] + sm[7];
    float mu = ts / SS;
    float var = (ts2 - SS * mu * mu) / (SS - 1);
    smu = mu;
    srs = rsqrtf(var + 2.220446049250313e-16f);
  }
  __syncthreads();
  float mu = smu, rs = srs;
  float scale = sqrtf(stats[BB + b] + 2.220446049250313e-16f);
  float mean0 = stats[b];
  for (int j = tid; j < SS; j += 256) {
    out[(size_t)b * SS + j] = (rowbuf[j] - mu) * rs * scale + mean0;
  }
}

extern "C" void kernel_launch(void* const* d_in, const int* in_sizes, int n_in,
                              void* d_out, int out_size, void* d_ws, size_t ws_size,
                              hipStream_t stream) {
  const float* x         = (const float*)d_in[0];
  const float* attn_ln_g = (const float*)d_in[1];
  const float* attn_ln_b = (const float*)d_in[2];
  const float* ipw       = (const float*)d_in[3];
  const float* ipb       = (const float*)d_in[4];
  const float* out_w     = (const float*)d_in[5];
  const float* out_b     = (const float*)d_in[6];
  const float* mlp_ln_g  = (const float*)d_in[7];
  const float* mlp_ln_b  = (const float*)d_in[8];
  const float* W1        = (const float*)d_in[9];
  const float* b1        = (const float*)d_in[10];
  const float* W2        = (const float*)d_in[11];
  const float* b2        = (const float*)d_in[12];

  float* ws    = (float*)d_ws;
  float* xA    = ws;                              // 65536 f (attn-0 output)
  float* xB    = xA + BB * SS;                    // 65536 f (attn-1 output)
  __bf16* ubf  = (__bf16*)(xB + BB * SS);         // 65536 bf16 (32768 f)
  __bf16* hbf  = (__bf16*)(xB + BB * SS + 32768); // 196608 bf16 (98304 f)
  float* part  = xB + BB * SS + 32768 + 98304;    // 786432 f (3.1 MB), [ks][b][s]
  float* stats = part + (size_t)KS2 * 32 * SS;    // 64 f
  float* pstat = stats + 64;                      // 512 f

  // ---- layer 0 ----
  k_attn<<<dim3(SS / 256, BB), 512, 0, stream>>>(x, xA,
                                                 attn_ln_g, attn_ln_b,
                                                 ipw, ipb, out_w, out_b,
                                                 stats, nullptr, nullptr, pstat);
  k_ln_bf<<<BB, 256, 0, stream>>>(xA, pstat, mlp_ln_g, mlp_ln_b, ubf);
  k_gemm1<<<EE / 32, 256, 0, stream>>>(ubf, W1, b1, hbf);
  k_gemm2<<<dim3(SS / 32, KS2), 256, 0, stream>>>(hbf, W2, part, EE);

  // ---- layer 1 (attn fuses layer-0 MLP tail) ----
  k_attn<<<dim3(SS / 256, BB), 512, 0, stream>>>(xA, xB,
                                                 attn_ln_g + SS, attn_ln_b + SS,
                                                 ipw + 3, ipb + 3, out_w + 1, out_b + 1,
                                                 nullptr, part, b2, pstat);
  k_ln_bf<<<BB, 256, 0, stream>>>(xB, pstat, mlp_ln_g + SS, mlp_ln_b + SS, ubf);
  k_gemm1<<<EE / 32, 256, 0, stream>>>(ubf, W1 + (size_t)EE * SS, b1 + EE, hbf);
  k_gemm2<<<dim3(SS / 32, KS2), 256, 0, stream>>>(hbf, W2 + (size_t)SS * EE, part, EE);

  // ---- final (fuses layer-1 MLP tail) ----
  k_final<<<BB, 256, 0, stream>>>(xB, part, b2 + SS, stats, (float*)d_out);
}